// Round 3
// baseline (1742.092 us; speedup 1.0000x reference)
//
#include <hip/hip_runtime.h>
#include <math.h>

#define HID 128
#define NSTEPS 64
#define SLEN 65
#define THREADS 128   // 2 waves
#define ROWS 32
#define ASTRIDE 136   // 128 + 8 f16 pad -> row-to-row bank rotation, 16B aligned
#define FSTRIDE 40    // 32 + 8 f16 pad

typedef _Float16 half8 __attribute__((ext_vector_type(8)));
typedef _Float16 half2v __attribute__((ext_vector_type(2)));
typedef float floatx4 __attribute__((ext_vector_type(4)));

// 4 WGs/CU (grid=1024, ~20KB LDS each). Each WG: 32 rows, 2 waves.
// Each wave owns 64 N-cols (4 nt tiles) x all 32 M-rows -> A-read redundancy x2
// (halved vs R2). Column pairing: tile pair p in {0,1}, t in {0,1}:
//   col(l15, nt=2p+t) = n_base + p*32 + 2*l15 + t
// so each lane's two t-values are ADJACENT columns -> b32 (half2) epilogue
// stores/reads, 2-way bank pattern (free), instead of scalar b16 (4-way).
__global__ __launch_bounds__(THREADS, 4)
void hedger(const float* __restrict__ S,
            const float* __restrict__ W0,  const float* __restrict__ b0,
            const float* __restrict__ rW1, const float* __restrict__ rb1,
            const float* __restrict__ rW2, const float* __restrict__ rb2,
            const float* __restrict__ sW1, const float* __restrict__ sb1,
            const float* __restrict__ sW2, const float* __restrict__ sb2,
            const float* __restrict__ Wf,  const float* __restrict__ bfp,
            float* __restrict__ out)
{
  __shared__ _Float16 bufA[ROWS * ASTRIDE];
  __shared__ _Float16 bufB[ROWS * ASTRIDE];
  __shared__ _Float16 featb[ROWS * FSTRIDE];
  __shared__ _Float16 WfS[HID];
  __shared__ float deltabuf[ROWS];

  const int tid  = threadIdx.x;
  const int wave = tid >> 6;            // 0..1
  const int lane = tid & 63;
  const int l15  = lane & 15;
  const int quad = lane >> 4;
  const int n_base = wave * 64;         // wave's 64-col N slice
  const int r0 = blockIdx.x * ROWS;

  // column owned by this lane for tile nt=2p+t
  int colof[4];
#pragma unroll
  for (int p = 0; p < 2; ++p)
#pragma unroll
    for (int t = 0; t < 2; ++t)
      colof[2 * p + t] = n_base + p * 32 + 2 * l15 + t;

  // ---- persistent B fragments: wave's 64-col slice of all 4 hidden matrices.
  // B-frag layout for 16x16x32: n -> colof[nt], k = quad*8 + j.  256 VGPRs.
  half8 wfrag[4][4][4];  // [matrix][kIter][nt]
  {
    const float* Wm[4] = {rW1, rW2, sW1, sW2};
#pragma unroll
    for (int m = 0; m < 4; ++m)
#pragma unroll
      for (int kq = 0; kq < 4; ++kq)
#pragma unroll
        for (int nt = 0; nt < 4; ++nt) {
          const int n  = colof[nt];
          const int kb = kq * 32 + quad * 8;
          half8 f;
#pragma unroll
          for (int j = 0; j < 8; ++j)
            f[j] = (_Float16)Wm[m][(kb + j) * HID + n];
          wfrag[m][kq][nt] = f;
        }
  }
  // W0 (8x128) as a K=32 zero-padded B operand: only quad 0 (k<8) is real.
  half8 w0frag[4];
#pragma unroll
  for (int nt = 0; nt < 4; ++nt) {
    const int n = colof[nt];
    half8 f;
#pragma unroll
    for (int j = 0; j < 8; ++j) {
      const int k = quad * 8 + j;
      f[j] = (k < 8) ? (_Float16)W0[k * HID + n] : (_Float16)0.f;
    }
    w0frag[nt] = f;
  }
  // biases for this lane's columns
  float b0r[4], rb1r[4], rb2r[4], sb1r[4], sb2r[4];
#pragma unroll
  for (int nt = 0; nt < 4; ++nt) {
    const int n = colof[nt];
    b0r[nt] = b0[n]; rb1r[nt] = rb1[n]; rb2r[nt] = rb2[n];
    sb1r[nt] = sb1[n]; sb2r[nt] = sb2[n];
  }
  const float bfv = bfp[0];

  // LDS init: zero feature pad (cols 8..31 stay zero), Wf, delta=0
  for (int i = tid; i < ROWS * FSTRIDE; i += THREADS) featb[i] = (_Float16)0.f;
  if (tid < HID)  WfS[tid] = (_Float16)Wf[tid];
  if (tid < ROWS) deltabuf[tid] = 0.f;

  // per-row feature state (threads 0..31 each own one row)
  float lm_prev = 0.f, cum_x = 0.f, qv = 0.f;
  const float* Srow = S + (size_t)(r0 + (tid & (ROWS - 1))) * SLEN;

  floatx4 acc[2][4];

// acc init = bias (fold the epilogue bias add)
#define INIT_BIAS(BR) do { \
  _Pragma("unroll") for (int mt = 0; mt < 2; ++mt) \
  _Pragma("unroll") for (int nt = 0; nt < 4; ++nt) { \
    floatx4 z = {BR[nt], BR[nt], BR[nt], BR[nt]}; acc[mt][nt] = z; } } while (0)

// acc init = bias + residual, reading half2 (b32) pairs of adjacent cols
#define INIT_BIAS_RES(BR, RESBUF) do { \
  _Pragma("unroll") for (int mt = 0; mt < 2; ++mt) \
  _Pragma("unroll") for (int p = 0; p < 2; ++p) \
  _Pragma("unroll") for (int r = 0; r < 4; ++r) { \
    const int row = mt * 16 + quad * 4 + r; \
    const half2v h2 = *(const half2v*)&RESBUF[row * ASTRIDE + n_base + p * 32 + 2 * l15]; \
    acc[mt][2 * p + 0][r] = BR[2 * p + 0] + (float)h2[0]; \
    acc[mt][2 * p + 1][r] = BR[2 * p + 1] + (float)h2[1]; \
  } } while (0)

#define GEMM128(SRC, MI) do { \
  _Pragma("unroll") for (int kq = 0; kq < 4; ++kq) { \
    half8 afr[2]; \
    _Pragma("unroll") for (int mt = 0; mt < 2; ++mt) \
      afr[mt] = *(const half8*)&SRC[(mt * 16 + l15) * ASTRIDE + kq * 32 + quad * 8]; \
    _Pragma("unroll") for (int mt = 0; mt < 2; ++mt) \
    _Pragma("unroll") for (int nt = 0; nt < 4; ++nt) \
      acc[mt][nt] = __builtin_amdgcn_mfma_f32_16x16x32_f16( \
          afr[mt], wfrag[MI][kq][nt], acc[mt][nt], 0, 0, 0); \
  } } while (0)

// lrelu(v)=max(v,0.2v); pack adjacent-col pair -> one b32 store (2-way: free)
#define EPI_LRELU(DST) do { \
  _Pragma("unroll") for (int mt = 0; mt < 2; ++mt) \
  _Pragma("unroll") for (int p = 0; p < 2; ++p) \
  _Pragma("unroll") for (int r = 0; r < 4; ++r) { \
    const int row = mt * 16 + quad * 4 + r; \
    const float v0 = acc[mt][2 * p + 0][r]; \
    const float v1 = acc[mt][2 * p + 1][r]; \
    half2v h2 = {(_Float16)fmaxf(v0, 0.2f * v0), (_Float16)fmaxf(v1, 0.2f * v1)}; \
    *(half2v*)&DST[row * ASTRIDE + n_base + p * 32 + 2 * l15] = h2; \
  } } while (0)

// plain paired store (bias+residual already folded into acc)
#define EPI_STORE(DST) do { \
  _Pragma("unroll") for (int mt = 0; mt < 2; ++mt) \
  _Pragma("unroll") for (int p = 0; p < 2; ++p) \
  _Pragma("unroll") for (int r = 0; r < 4; ++r) { \
    const int row = mt * 16 + quad * 4 + r; \
    half2v h2 = {(_Float16)acc[mt][2 * p + 0][r], (_Float16)acc[mt][2 * p + 1][r]}; \
    *(half2v*)&DST[row * ASTRIDE + n_base + p * 32 + 2 * l15] = h2; \
  } } while (0)

#pragma unroll 1
  for (int k = 0; k < NSTEPS; ++k) {
    __syncthreads();  // deltabuf ready; prior-step bufA readers done
    if (tid < ROWS) {
      const float lm = logf(Srow[k] * 0.01f);  // log(S/S0), S0=100
      if (k > 0) { const float r = lm - lm_prev; qv += r * r; }
      lm_prev = lm;
      cum_x += lm;
      const float tT = (float)k * (1.f / 64.f);
      _Float16* fr = &featb[tid * FSTRIDE];
      fr[0] = (_Float16)lm;                              // x
      fr[1] = (_Float16)(1.f - tT);                      // tau
      fr[2] = (_Float16)0.235f;                          // sqrt(XI0)
      fr[3] = (_Float16)deltabuf[tid];                   // delta_prev
      fr[4] = (_Float16)(cum_x / (float)(k + 1));        // run_mean
      fr[5] = (_Float16)qv;                              // qv
      fr[6] = (_Float16)(1.9f * sqrtf(qv + 1e-12f));     // eta*sqrt(qv+eps)
      fr[7] = (_Float16)tT;                              // t/T
    }
    __syncthreads();

    // G0: h0 = lrelu(featPad @ W0pad + b0)   (single K=32 iter)
    INIT_BIAS(b0r);
    {
      half8 afr[2];
#pragma unroll
      for (int mt = 0; mt < 2; ++mt)
        afr[mt] = *(const half8*)&featb[(mt * 16 + l15) * FSTRIDE + quad * 8];
#pragma unroll
      for (int mt = 0; mt < 2; ++mt)
#pragma unroll
        for (int nt = 0; nt < 4; ++nt)
          acc[mt][nt] = __builtin_amdgcn_mfma_f32_16x16x32_f16(
              afr[mt], w0frag[nt], acc[mt][nt], 0, 0, 0);
    }
    EPI_LRELU(bufA);
    __syncthreads();

    INIT_BIAS(rb1r);            GEMM128(bufA, 0); EPI_LRELU(bufB);  // u = lrelu(h0@rW1+rb1)
    __syncthreads();
    INIT_BIAS_RES(rb2r, bufA);  GEMM128(bufB, 1); EPI_STORE(bufA);  // h1 = h0 + u@rW2+rb2
    __syncthreads();
    INIT_BIAS(sb1r);            GEMM128(bufA, 2); EPI_LRELU(bufB);  // v = lrelu(h1@sW1+sb1)
    __syncthreads();
    INIT_BIAS_RES(sb2r, bufA);  GEMM128(bufB, 3); EPI_STORE(bufA);  // h2 = h1 + v@sW2+sb2
    __syncthreads();

    // final: delta = sigmoid(h2 @ Wf + bf); wave covers 16 rows, quads split K
    {
      const int row = wave * 16 + l15;
      const _Float16* hr = &bufA[row * ASTRIDE + quad * 32];
      const _Float16* wr = &WfS[quad * 32];
      float s = 0.f;
#pragma unroll
      for (int u = 0; u < 4; ++u) {
        const half8 h = *(const half8*)&hr[u * 8];
        const half8 w = *(const half8*)&wr[u * 8];
#pragma unroll
        for (int j = 0; j < 8; ++j) s += (float)h[j] * (float)w[j];
      }
      s += __shfl_xor(s, 16);
      s += __shfl_xor(s, 32);
      const float d = 1.f / (1.f + expf(-(s + bfv)));
      if (quad == 0) {
        deltabuf[row] = d;
        out[(size_t)(r0 + row) * NSTEPS + k] = d;
      }
    }
  }
#undef INIT_BIAS
#undef INIT_BIAS_RES
#undef GEMM128
#undef EPI_LRELU
#undef EPI_STORE
}

extern "C" void kernel_launch(void* const* d_in, const int* in_sizes, int n_in,
                              void* d_out, int out_size, void* d_ws, size_t ws_size,
                              hipStream_t stream) {
  const float* S   = (const float*)d_in[0];
  const float* W0  = (const float*)d_in[1];
  const float* b0  = (const float*)d_in[2];
  const float* rW1 = (const float*)d_in[3];
  const float* rb1 = (const float*)d_in[4];
  const float* rW2 = (const float*)d_in[5];
  const float* rb2 = (const float*)d_in[6];
  const float* sW1 = (const float*)d_in[7];
  const float* sb1 = (const float*)d_in[8];
  const float* sW2 = (const float*)d_in[9];
  const float* sb2 = (const float*)d_in[10];
  const float* Wf  = (const float*)d_in[11];
  const float* bf  = (const float*)d_in[12];
  float* out = (float*)d_out;

  const int B = out_size / NSTEPS;        // 32768
  const int nblocks = B / ROWS;           // 1024 WGs -> 4 per CU
  hedger<<<nblocks, THREADS, 0, stream>>>(
      S, W0, b0, rW1, rb1, rW2, rb2, sW1, sb1, sW2, sb2, Wf, bf, out);
}

// Round 4
// 434.661 us; speedup vs baseline: 4.0079x; 4.0079x over previous
//
#include <hip/hip_runtime.h>
#include <math.h>

#define HID 128
#define NSTEPS 64
#define SLEN 65
#define THREADS 256
#define ROWS 64
#define ASTRIDE 136   // 128 + 8 f16 pad -> row-to-row bank rotation, 16B aligned
#define FSTRIDE 40    // 32 + 8 f16 pad

typedef _Float16 half8 __attribute__((ext_vector_type(8)));
typedef _Float16 half2v __attribute__((ext_vector_type(2)));
typedef float floatx4 __attribute__((ext_vector_type(4)));

// 2 WGs/CU (grid=512, ~41KB LDS each). Each WG: 64 rows, 4 waves.
// Wave owns a 32-col N slice (wfrag = 128 VGPR, fits the 256-VGPR cap at
// 2 waves/SIMD -- R3 proved 64-col/wave = 256 VGPR spills to scratch, 5.3GB HBM).
// Column pairing within the slice: tile nt=t, col(l15,t) = n_base + 2*l15 + t,
// so each lane owns ADJACENT columns (t=0,1) -> epilogue/residual LDS traffic is
// b32 half2 (2-way bank pattern, free per m136) instead of scalar b16 (4-way).
__global__ __launch_bounds__(THREADS, 2)
void hedger(const float* __restrict__ S,
            const float* __restrict__ W0,  const float* __restrict__ b0,
            const float* __restrict__ rW1, const float* __restrict__ rb1,
            const float* __restrict__ rW2, const float* __restrict__ rb2,
            const float* __restrict__ sW1, const float* __restrict__ sb1,
            const float* __restrict__ sW2, const float* __restrict__ sb2,
            const float* __restrict__ Wf,  const float* __restrict__ bfp,
            float* __restrict__ out)
{
  __shared__ _Float16 bufA[ROWS * ASTRIDE];
  __shared__ _Float16 bufB[ROWS * ASTRIDE];
  __shared__ _Float16 featb[ROWS * FSTRIDE];
  __shared__ _Float16 WfS[HID];
  __shared__ float deltabuf[ROWS];

  const int tid  = threadIdx.x;
  const int wave = tid >> 6;            // 0..3
  const int lane = tid & 63;
  const int l15  = lane & 15;
  const int quad = lane >> 4;
  const int n_base = wave * 32;         // wave's 32-col N slice
  const int r0 = blockIdx.x * ROWS;

  // column owned by this lane for tile nt (adjacent pair)
  const int col0 = n_base + 2 * l15;    // tile nt covers col0 + nt, nt in {0,1}

  // ---- persistent B fragments: wave's 32-col slice of all 4 hidden matrices.
  // B-frag layout for 16x16x32: n = col0 + nt, k = quad*8 + j.  128 VGPRs.
  half8 wfrag[4][4][2];  // [matrix][kIter][nt]
  {
    const float* Wm[4] = {rW1, rW2, sW1, sW2};
#pragma unroll
    for (int m = 0; m < 4; ++m)
#pragma unroll
      for (int kq = 0; kq < 4; ++kq)
#pragma unroll
        for (int nt = 0; nt < 2; ++nt) {
          const int n  = col0 + nt;
          const int kb = kq * 32 + quad * 8;
          half8 f;
#pragma unroll
          for (int j = 0; j < 8; ++j)
            f[j] = (_Float16)Wm[m][(kb + j) * HID + n];
          wfrag[m][kq][nt] = f;
        }
  }
  // W0 (8x128) as a K=32 zero-padded B operand: only quad 0 (k<8) is real.
  half8 w0frag[2];
#pragma unroll
  for (int nt = 0; nt < 2; ++nt) {
    const int n = col0 + nt;
    half8 f;
#pragma unroll
    for (int j = 0; j < 8; ++j) {
      const int k = quad * 8 + j;
      f[j] = (k < 8) ? (_Float16)W0[k * HID + n] : (_Float16)0.f;
    }
    w0frag[nt] = f;
  }
  // biases for this lane's columns
  float b0r[2], rb1r[2], rb2r[2], sb1r[2], sb2r[2];
#pragma unroll
  for (int nt = 0; nt < 2; ++nt) {
    const int n = col0 + nt;
    b0r[nt] = b0[n]; rb1r[nt] = rb1[n]; rb2r[nt] = rb2[n];
    sb1r[nt] = sb1[n]; sb2r[nt] = sb2[n];
  }
  const float bfv = bfp[0];

  // LDS init: zero feature pad (cols 8..31 stay zero forever), Wf, delta=0
  for (int i = tid; i < ROWS * FSTRIDE; i += THREADS) featb[i] = (_Float16)0.f;
  if (tid < HID)  WfS[tid] = (_Float16)Wf[tid];
  if (tid < ROWS) deltabuf[tid] = 0.f;

  // per-row feature state (threads 0..63 each own one row)
  float lm_prev = 0.f, cum_x = 0.f, qv = 0.f;
  const float* Srow = S + (size_t)(r0 + (tid & (ROWS - 1))) * SLEN;

  floatx4 acc[4][2];

// acc init = bias (fold the epilogue bias add)
#define INIT_BIAS(BR) do { \
  _Pragma("unroll") for (int mt = 0; mt < 4; ++mt) \
  _Pragma("unroll") for (int nt = 0; nt < 2; ++nt) { \
    floatx4 z = {BR[nt], BR[nt], BR[nt], BR[nt]}; acc[mt][nt] = z; } } while (0)

// acc init = bias + residual, reading half2 (b32) pairs of adjacent cols
#define INIT_BIAS_RES(BR, RESBUF) do { \
  _Pragma("unroll") for (int mt = 0; mt < 4; ++mt) \
  _Pragma("unroll") for (int r = 0; r < 4; ++r) { \
    const int row = mt * 16 + quad * 4 + r; \
    const half2v h2 = *(const half2v*)&RESBUF[row * ASTRIDE + col0]; \
    acc[mt][0][r] = BR[0] + (float)h2[0]; \
    acc[mt][1][r] = BR[1] + (float)h2[1]; \
  } } while (0)

#define GEMM128(SRC, MI) do { \
  _Pragma("unroll") for (int kq = 0; kq < 4; ++kq) { \
    half8 afr[4]; \
    _Pragma("unroll") for (int mt = 0; mt < 4; ++mt) \
      afr[mt] = *(const half8*)&SRC[(mt * 16 + l15) * ASTRIDE + kq * 32 + quad * 8]; \
    _Pragma("unroll") for (int mt = 0; mt < 4; ++mt) \
    _Pragma("unroll") for (int nt = 0; nt < 2; ++nt) \
      acc[mt][nt] = __builtin_amdgcn_mfma_f32_16x16x32_f16( \
          afr[mt], wfrag[MI][kq][nt], acc[mt][nt], 0, 0, 0); \
  } } while (0)

// lrelu(v)=max(v,0.2v); pack adjacent-col pair -> one b32 store (2-way: free)
#define EPI_LRELU(DST) do { \
  _Pragma("unroll") for (int mt = 0; mt < 4; ++mt) \
  _Pragma("unroll") for (int r = 0; r < 4; ++r) { \
    const int row = mt * 16 + quad * 4 + r; \
    const float v0 = acc[mt][0][r]; \
    const float v1 = acc[mt][1][r]; \
    half2v h2 = {(_Float16)fmaxf(v0, 0.2f * v0), (_Float16)fmaxf(v1, 0.2f * v1)}; \
    *(half2v*)&DST[row * ASTRIDE + col0] = h2; \
  } } while (0)

// plain paired store (bias+residual already folded into acc)
#define EPI_STORE(DST) do { \
  _Pragma("unroll") for (int mt = 0; mt < 4; ++mt) \
  _Pragma("unroll") for (int r = 0; r < 4; ++r) { \
    const int row = mt * 16 + quad * 4 + r; \
    half2v h2 = {(_Float16)acc[mt][0][r], (_Float16)acc[mt][1][r]}; \
    *(half2v*)&DST[row * ASTRIDE + col0] = h2; \
  } } while (0)

#pragma unroll 1
  for (int k = 0; k < NSTEPS; ++k) {
    __syncthreads();  // deltabuf ready; prior-step bufA readers done
    if (tid < ROWS) {
      const float lm = logf(Srow[k] * 0.01f);  // log(S/S0), S0=100
      if (k > 0) { const float r = lm - lm_prev; qv += r * r; }
      lm_prev = lm;
      cum_x += lm;
      const float tT = (float)k * (1.f / 64.f);
      _Float16* fr = &featb[tid * FSTRIDE];
      fr[0] = (_Float16)lm;                              // x
      fr[1] = (_Float16)(1.f - tT);                      // tau
      fr[2] = (_Float16)0.235f;                          // sqrt(XI0)
      fr[3] = (_Float16)deltabuf[tid];                   // delta_prev
      fr[4] = (_Float16)(cum_x / (float)(k + 1));        // run_mean
      fr[5] = (_Float16)qv;                              // qv
      fr[6] = (_Float16)(1.9f * sqrtf(qv + 1e-12f));     // eta*sqrt(qv+eps)
      fr[7] = (_Float16)tT;                              // t/T
    }
    __syncthreads();

    // G0: h0 = lrelu(featPad @ W0pad + b0)   (single K=32 iter)
    INIT_BIAS(b0r);
    {
      half8 afr[4];
#pragma unroll
      for (int mt = 0; mt < 4; ++mt)
        afr[mt] = *(const half8*)&featb[(mt * 16 + l15) * FSTRIDE + quad * 8];
#pragma unroll
      for (int mt = 0; mt < 4; ++mt)
#pragma unroll
        for (int nt = 0; nt < 2; ++nt)
          acc[mt][nt] = __builtin_amdgcn_mfma_f32_16x16x32_f16(
              afr[mt], w0frag[nt], acc[mt][nt], 0, 0, 0);
    }
    EPI_LRELU(bufA);
    __syncthreads();

    INIT_BIAS(rb1r);            GEMM128(bufA, 0); EPI_LRELU(bufB);  // u = lrelu(h0@rW1+rb1)
    __syncthreads();
    INIT_BIAS_RES(rb2r, bufA);  GEMM128(bufB, 1); EPI_STORE(bufA);  // h1 = h0 + u@rW2+rb2
    __syncthreads();
    INIT_BIAS(sb1r);            GEMM128(bufA, 2); EPI_LRELU(bufB);  // v = lrelu(h1@sW1+sb1)
    __syncthreads();
    INIT_BIAS_RES(sb2r, bufA);  GEMM128(bufB, 3); EPI_STORE(bufA);  // h2 = h1 + v@sW2+sb2
    __syncthreads();

    // final: delta = sigmoid(h2 @ Wf + bf); each wave covers 16 rows, quads split K
    {
      const int row = wave * 16 + l15;
      const _Float16* hr = &bufA[row * ASTRIDE + quad * 32];
      const _Float16* wr = &WfS[quad * 32];
      float s = 0.f;
#pragma unroll
      for (int u = 0; u < 4; ++u) {
        const half8 h = *(const half8*)&hr[u * 8];
        const half8 w = *(const half8*)&wr[u * 8];
#pragma unroll
        for (int j = 0; j < 8; ++j) s += (float)h[j] * (float)w[j];
      }
      s += __shfl_xor(s, 16);
      s += __shfl_xor(s, 32);
      const float d = 1.f / (1.f + expf(-(s + bfv)));
      if (quad == 0) {
        deltabuf[row] = d;
        out[(size_t)(r0 + row) * NSTEPS + k] = d;
      }
    }
  }
#undef INIT_BIAS
#undef INIT_BIAS_RES
#undef GEMM128
#undef EPI_LRELU
#undef EPI_STORE
}

extern "C" void kernel_launch(void* const* d_in, const int* in_sizes, int n_in,
                              void* d_out, int out_size, void* d_ws, size_t ws_size,
                              hipStream_t stream) {
  const float* S   = (const float*)d_in[0];
  const float* W0  = (const float*)d_in[1];
  const float* b0  = (const float*)d_in[2];
  const float* rW1 = (const float*)d_in[3];
  const float* rb1 = (const float*)d_in[4];
  const float* rW2 = (const float*)d_in[5];
  const float* rb2 = (const float*)d_in[6];
  const float* sW1 = (const float*)d_in[7];
  const float* sb1 = (const float*)d_in[8];
  const float* sW2 = (const float*)d_in[9];
  const float* sb2 = (const float*)d_in[10];
  const float* Wf  = (const float*)d_in[11];
  const float* bf  = (const float*)d_in[12];
  float* out = (float*)d_out;

  const int B = out_size / NSTEPS;        // 32768
  const int nblocks = B / ROWS;           // 512 WGs -> 2 per CU
  hedger<<<nblocks, THREADS, 0, stream>>>(
      S, W0, b0, rW1, rb1, rW2, rb2, sW1, sb1, sW2, sb2, Wf, bf, out);
}

// Round 9
// 416.656 us; speedup vs baseline: 4.1811x; 1.0432x over previous
//
#include <hip/hip_runtime.h>
#include <math.h>

#define HID 128
#define NSTEPS 64
#define SLEN 65
#define THREADS 256
#define ROWS 64
#define ASTRIDE 136   // 128 + 8 f16 pad, 16B aligned rows
#define FSTRIDE 40    // 32 + 8 f16 pad

typedef _Float16 half8 __attribute__((ext_vector_type(8)));
typedef __fp16 fp16x2 __attribute__((ext_vector_type(2)));
typedef float floatx4 __attribute__((ext_vector_type(4)));

// 2 WGs/CU (grid=512). 4 waves/WG; wave owns a 32-col N slice (wfrag=128 VGPR;
// R3: 64-col/wave spills). Lane owns ADJACENT cols col0,col0+1 -> b32 paired
// epilogue traffic. 6 barriers/step; delta-independent features of step k+1
// computed inside the GEMM phase.
// R6/R7/R8 POST-MORTEM: the bit-identical absmax 1.17e-2 across three numerics
// variants was a RACE — step-0 feature writes and the strided featb zero-fill
// were in the same barrier interval; row r's feature bytes are zeroed by a
// DIFFERENT thread ((40r+j) mod 256) than the writer (thread r). Fixed with a
// __syncthreads() between zero-fill and step-0 feature write.
__global__ __launch_bounds__(THREADS, 2)
void hedger(const float* __restrict__ S,
            const float* __restrict__ W0,  const float* __restrict__ b0,
            const float* __restrict__ rW1, const float* __restrict__ rb1,
            const float* __restrict__ rW2, const float* __restrict__ rb2,
            const float* __restrict__ sW1, const float* __restrict__ sb1,
            const float* __restrict__ sW2, const float* __restrict__ sb2,
            const float* __restrict__ Wf,  const float* __restrict__ bfp,
            float* __restrict__ out)
{
  __shared__ _Float16 bufA[ROWS * ASTRIDE];
  __shared__ _Float16 bufB[ROWS * ASTRIDE];
  __shared__ _Float16 featb[ROWS * FSTRIDE];
  __shared__ _Float16 WfS[HID];

  const int tid  = threadIdx.x;
  const int wave = tid >> 6;            // 0..3
  const int lane = tid & 63;
  const int l15  = lane & 15;
  const int quad = lane >> 4;
  const int n_base = wave * 32;
  const int r0 = blockIdx.x * ROWS;
  const int col0 = n_base + 2 * l15;    // lane's adjacent column pair

  // ---- persistent B fragments (128 VGPR): n = col0 + nt, k = quad*8 + j.
  half8 wfrag[4][4][2];  // [matrix][kIter][nt]
  {
    const float* Wm[4] = {rW1, rW2, sW1, sW2};
#pragma unroll
    for (int m = 0; m < 4; ++m)
#pragma unroll
      for (int kq = 0; kq < 4; ++kq)
#pragma unroll
        for (int nt = 0; nt < 2; ++nt) {
          const int n  = col0 + nt;
          const int kb = kq * 32 + quad * 8;
          half8 f;
#pragma unroll
          for (int j = 0; j < 8; ++j)
            f[j] = (_Float16)Wm[m][(kb + j) * HID + n];
          wfrag[m][kq][nt] = f;
        }
  }
  // W0 (8x128) zero-padded to K=32: only quad 0 (k<8) is real.
  half8 w0frag[2];
#pragma unroll
  for (int nt = 0; nt < 2; ++nt) {
    const int n = col0 + nt;
    half8 f;
#pragma unroll
    for (int j = 0; j < 8; ++j) {
      const int k = quad * 8 + j;
      f[j] = (k < 8) ? (_Float16)W0[k * HID + n] : (_Float16)0.f;
    }
    w0frag[nt] = f;
  }
  // biases for this lane's columns
  float b0r[2], rb1r[2], rb2r[2], sb1r[2], sb2r[2];
#pragma unroll
  for (int nt = 0; nt < 2; ++nt) {
    const int n = col0 + nt;
    b0r[nt] = b0[n]; rb1r[nt] = rb1[n]; rb2r[nt] = rb2[n];
    sb1r[nt] = sb1[n]; sb2r[nt] = sb2[n];
  }
  const float bfv = bfp[0];

  // LDS zero-fill (pad cols 8..31 stay zero forever) + Wf
  for (int i = tid; i < ROWS * FSTRIDE; i += THREADS) featb[i] = (_Float16)0.f;
  if (tid < HID) WfS[tid] = (_Float16)Wf[tid];
  __syncthreads();   // RACE FIX: zero-fill must complete before feature writes

  // step-0 features (threads 0..63 each own one row)
  float lm_prev = 0.f, cum_x = 0.f, qv = 0.f;
  const float* Srow = S + (size_t)(r0 + (tid & (ROWS - 1))) * SLEN;
  if (tid < ROWS) {
    const float lm = logf(Srow[0] * 0.01f);
    lm_prev = lm; cum_x = lm; qv = 0.f;
    _Float16* fr = &featb[tid * FSTRIDE];
    fr[0] = (_Float16)lm;
    fr[1] = (_Float16)1.0f;
    fr[2] = (_Float16)0.235f;
    fr[3] = (_Float16)0.f;                 // delta_0 = 0
    fr[4] = (_Float16)lm;                  // run_mean at k=0
    fr[5] = (_Float16)0.f;
    fr[6] = (_Float16)(1.9f * sqrtf(1e-12f));
    fr[7] = (_Float16)0.f;
  }
  __syncthreads();

  floatx4 acc[4][2];

#define INIT_BIAS(BR) do { \
  _Pragma("unroll") for (int mt = 0; mt < 4; ++mt) \
  _Pragma("unroll") for (int nt = 0; nt < 2; ++nt) { \
    floatx4 z = {BR[nt], BR[nt], BR[nt], BR[nt]}; acc[mt][nt] = z; } } while (0)

#define INIT_BIAS_RES(BR, RESBUF) do { \
  _Pragma("unroll") for (int mt = 0; mt < 4; ++mt) \
  _Pragma("unroll") for (int r = 0; r < 4; ++r) { \
    const int row = mt * 16 + quad * 4 + r; \
    const fp16x2 h2 = *(const fp16x2*)&RESBUF[row * ASTRIDE + col0]; \
    acc[mt][0][r] = BR[0] + (float)h2[0]; \
    acc[mt][1][r] = BR[1] + (float)h2[1]; \
  } } while (0)

#define GEMM128(SRC, MI) do { \
  _Pragma("unroll") for (int kq = 0; kq < 4; ++kq) { \
    half8 afr[4]; \
    _Pragma("unroll") for (int mt = 0; mt < 4; ++mt) \
      afr[mt] = *(const half8*)&SRC[(mt * 16 + l15) * ASTRIDE + kq * 32 + quad * 8]; \
    _Pragma("unroll") for (int mt = 0; mt < 4; ++mt) \
    _Pragma("unroll") for (int nt = 0; nt < 2; ++nt) \
      acc[mt][nt] = __builtin_amdgcn_mfma_f32_16x16x32_f16( \
          afr[mt], wfrag[MI][kq][nt], acc[mt][nt], 0, 0, 0); \
  } } while (0)

// lrelu in f32, RTN casts, pack pair -> one b32 store (R4 numerics)
#define EPI_LRELU(DST) do { \
  _Pragma("unroll") for (int mt = 0; mt < 4; ++mt) \
  _Pragma("unroll") for (int r = 0; r < 4; ++r) { \
    const int row = mt * 16 + quad * 4 + r; \
    const float v0 = acc[mt][0][r]; \
    const float v1 = acc[mt][1][r]; \
    fp16x2 h2 = {(__fp16)fmaxf(v0, 0.2f * v0), (__fp16)fmaxf(v1, 0.2f * v1)}; \
    *(fp16x2*)&DST[row * ASTRIDE + col0] = h2; \
  } } while (0)

#define EPI_STORE(DST) do { \
  _Pragma("unroll") for (int mt = 0; mt < 4; ++mt) \
  _Pragma("unroll") for (int r = 0; r < 4; ++r) { \
    const int row = mt * 16 + quad * 4 + r; \
    fp16x2 h2 = {(__fp16)acc[mt][0][r], (__fp16)acc[mt][1][r]}; \
    *(fp16x2*)&DST[row * ASTRIDE + col0] = h2; \
  } } while (0)

#pragma unroll 1
  for (int k = 0; k < NSTEPS; ++k) {
    // G0: h0 = lrelu(featPad @ W0pad + b0)   (featb complete: fr[3] via bar F)
    INIT_BIAS(b0r);
    {
      half8 afr[4];
#pragma unroll
      for (int mt = 0; mt < 4; ++mt)
        afr[mt] = *(const half8*)&featb[(mt * 16 + l15) * FSTRIDE + quad * 8];
#pragma unroll
      for (int mt = 0; mt < 4; ++mt)
#pragma unroll
        for (int nt = 0; nt < 2; ++nt)
          acc[mt][nt] = __builtin_amdgcn_mfma_f32_16x16x32_f16(
              afr[mt], w0frag[nt], acc[mt][nt], 0, 0, 0);
    }
    EPI_LRELU(bufA);
    __syncthreads();                                   // bar A: bufA ready, featb consumed

    // delta-independent features of step k+1 — overlaps the GEMM phase.
    // (Srow[k+1] valid at k=63: SLEN=65; write is dead then, harmless.)
    if (tid < ROWS) {
      const int kk = k + 1;
      const float lm = logf(Srow[kk] * 0.01f);
      const float rr = lm - lm_prev; qv += rr * rr;
      lm_prev = lm; cum_x += lm;
      const float tT = (float)kk * (1.f / 64.f);
      _Float16* fr = &featb[tid * FSTRIDE];
      fr[0] = (_Float16)lm;
      fr[1] = (_Float16)(1.f - tT);
      fr[4] = (_Float16)(cum_x / (float)(kk + 1));
      fr[5] = (_Float16)qv;
      fr[6] = (_Float16)(1.9f * sqrtf(qv + 1e-12f));
      fr[7] = (_Float16)tT;
    }

    INIT_BIAS(rb1r);            GEMM128(bufA, 0); EPI_LRELU(bufB);  // u
    __syncthreads();                                   // bar B
    INIT_BIAS_RES(rb2r, bufA);  GEMM128(bufB, 1); EPI_STORE(bufA);  // h1
    __syncthreads();                                   // bar C
    INIT_BIAS(sb1r);            GEMM128(bufA, 2); EPI_LRELU(bufB);  // v
    __syncthreads();                                   // bar D
    INIT_BIAS_RES(sb2r, bufA);  GEMM128(bufB, 3); EPI_STORE(bufA);  // h2
    __syncthreads();                                   // bar E: h2 in bufA

    // delta = sigmoid(h2 @ Wf + bf); wave covers 16 rows, quads split K.
    // f32-convert + FMA (R4 numerics).
    {
      const int row = wave * 16 + l15;
      const _Float16* hr = &bufA[row * ASTRIDE + quad * 32];
      const _Float16* wr = &WfS[quad * 32];
      float s = 0.f;
#pragma unroll
      for (int u = 0; u < 4; ++u) {
        const half8 h = *(const half8*)&hr[u * 8];
        const half8 w = *(const half8*)&wr[u * 8];
#pragma unroll
        for (int j = 0; j < 8; ++j) s += (float)h[j] * (float)w[j];
      }
      s += __shfl_xor(s, 16);
      s += __shfl_xor(s, 32);
      const float d = 1.f / (1.f + expf(-(s + bfv)));
      if (quad == 0) {
        featb[row * FSTRIDE + 3] = (_Float16)d;        // fr[3] for step k+1
        out[(size_t)(r0 + row) * NSTEPS + k] = d;
      }
    }
    __syncthreads();                                   // bar F: featb complete
  }
#undef INIT_BIAS
#undef INIT_BIAS_RES
#undef GEMM128
#undef EPI_LRELU
#undef EPI_STORE
}

extern "C" void kernel_launch(void* const* d_in, const int* in_sizes, int n_in,
                              void* d_out, int out_size, void* d_ws, size_t ws_size,
                              hipStream_t stream) {
  const float* S   = (const float*)d_in[0];
  const float* W0  = (const float*)d_in[1];
  const float* b0  = (const float*)d_in[2];
  const float* rW1 = (const float*)d_in[3];
  const float* rb1 = (const float*)d_in[4];
  const float* rW2 = (const float*)d_in[5];
  const float* rb2 = (const float*)d_in[6];
  const float* sW1 = (const float*)d_in[7];
  const float* sb1 = (const float*)d_in[8];
  const float* sW2 = (const float*)d_in[9];
  const float* sb2 = (const float*)d_in[10];
  const float* Wf  = (const float*)d_in[11];
  const float* bf  = (const float*)d_in[12];
  float* out = (float*)d_out;

  const int B = out_size / NSTEPS;        // 32768
  const int nblocks = B / ROWS;           // 512 WGs -> 2 per CU
  hedger<<<nblocks, THREADS, 0, stream>>>(
      S, W0, b0, rW1, rb1, rW2, rb2, sW1, sb1, sW2, sb2, Wf, bf, out);
}